// Round 10
// baseline (217.153 us; speedup 1.0000x reference)
//
#include <hip/hip_runtime.h>

#define HID 64
#define WST 72   // wlds row stride in ushorts (144B rows, 16B-aligned frag slices)

typedef __attribute__((ext_vector_type(8))) short bf16x8;
typedef __attribute__((ext_vector_type(4))) float f32x4;

__device__ __forceinline__ unsigned short f2bf(float f) {
    // round-to-nearest-even bf16
    unsigned int u = __float_as_uint(f);
    return (unsigned short)((u + 0x7fffu + ((u >> 16) & 1u)) >> 16);
}

__device__ __forceinline__ unsigned int pack2bf(float lo, float hi) {
    unsigned int ul = __float_as_uint(lo), uh = __float_as_uint(hi);
    unsigned int rl = (ul + 0x7fffu + ((ul >> 16) & 1u)) >> 16;
    unsigned int rh = (uh + 0x7fffu + ((uh >> 16) & 1u)) & 0xffff0000u;
    return rl | rh;
}

// zb[n][k] = bf16(z[n][k]) -- 128B rows, the only "prep" phase (streaming).
__global__ __launch_bounds__(256) void zconv_kernel(
    const float* __restrict__ z, uint4* __restrict__ zb, int n4)
{
    const int t = blockIdx.x * 256 + threadIdx.x;
    if (t < n4) {
        const float4 f0 = ((const float4*)z)[2 * t];
        const float4 f1 = ((const float4*)z)[2 * t + 1];
        uint4 u;
        u.x = pack2bf(f0.x, f0.y); u.y = pack2bf(f0.z, f0.w);
        u.z = pack2bf(f1.x, f1.y); u.w = pack2bf(f1.z, f1.w);
        zb[t] = u;
    }
}

// Single fused edge kernel:
//   out[e] = relu( zb[row[e]] @ W1[:64] + zb[col[e]] @ W1[64:] + b1 ) . W2 + b2
// Per 64-edge chunk (one wave): 16 uint4 gathers (16-deep MLP, full 128B rows),
// then 4 M-tiles x 4 N-tiles x (2 K-steps x 2 sides) mfma_f32_16x16x32_bf16.
// W1 is staged once per block into LDS as bf16 in frag-friendly layout
// wlds[c][k], c = (side<<6)|outcol, k = 0..63.
__global__ __launch_bounds__(256) void edge_mfma_kernel(
    const int* __restrict__ row, const int* __restrict__ col,
    const unsigned short* __restrict__ zb,
    const float* __restrict__ W1, const float* __restrict__ b1,
    const float* __restrict__ W2, const float* __restrict__ b2,
    float* __restrict__ out, int nchunks)
{
    __shared__ alignas(16) unsigned short wlds[128 * WST];

    const int t    = threadIdx.x;
    const int lane = t & 63;
    const int q    = lane >> 4;     // k-group / D row-group
    const int r    = lane & 15;     // A-row (edge) / B-col (hid)

    // stage W1 [128][64] f32 -> wlds (coalesced float4 reads, one-time)
#pragma unroll
    for (int i = 0; i < 8; ++i) {
        const int f  = t + i * 256;          // float4 id 0..2047
        const int kk = f >> 4;               // W1 row 0..127
        const int j4 = f & 15;               // 4-col group
        const int cb = (kk & 64) + j4 * 4;   // c base: side bit + col
        const int k  = kk & 63;
        const float4 v = ((const float4*)W1)[f];
        wlds[(cb + 0) * WST + k] = f2bf(v.x);
        wlds[(cb + 1) * WST + k] = f2bf(v.y);
        wlds[(cb + 2) * WST + k] = f2bf(v.z);
        wlds[(cb + 3) * WST + k] = f2bf(v.w);
    }
    __syncthreads();

    float w2r[4], bias[4];
#pragma unroll
    for (int nt = 0; nt < 4; ++nt) {
        w2r[nt]  = W2[nt * 16 + r];
        bias[nt] = b1[nt * 16 + r];
    }
    const float b2v = b2[0];

    const int wid = (blockIdx.x * 256 + t) >> 6;
    const int nw  = (gridDim.x * 256) >> 6;

    for (int ch = wid; ch < nchunks; ch += nw) {
        const int ebase = ch << 6;
        const int ridx = row[ebase + lane];   // coalesced
        const int cidx = col[ebase + lane];

        // 16-deep gather: per M-tile, lane (q,r) pulls 16B of edge (mt*16+r)'s
        // zb row at dim offset q*8 (+32 for K-step 1)
        uint4 gr[4][2], gc[4][2];
#pragma unroll
        for (int mt = 0; mt < 4; ++mt) {
            const int er = __shfl(ridx, mt * 16 + r);
            const int ec = __shfl(cidx, mt * 16 + r);
            const unsigned short* pr = zb + (size_t)er * HID + q * 8;
            const unsigned short* pc = zb + (size_t)ec * HID + q * 8;
            gr[mt][0] = *(const uint4*)pr;
            gr[mt][1] = *(const uint4*)(pr + 32);
            gc[mt][0] = *(const uint4*)pc;
            gc[mt][1] = *(const uint4*)(pc + 32);
        }

        f32x4 part[4] = {{0,0,0,0},{0,0,0,0},{0,0,0,0},{0,0,0,0}};
#pragma unroll
        for (int nt = 0; nt < 4; ++nt) {
            const unsigned short* wp = wlds + (nt * 16 + r) * WST + q * 8;
            const bf16x8 wa0 = *(const bf16x8*)wp;                  // side A, ks0
            const bf16x8 wa1 = *(const bf16x8*)(wp + 32);           // side A, ks1
            const bf16x8 wb0 = *(const bf16x8*)(wp + 64 * WST);     // side B, ks0
            const bf16x8 wb1 = *(const bf16x8*)(wp + 64 * WST + 32);
#pragma unroll
            for (int mt = 0; mt < 4; ++mt) {
                f32x4 acc = {0.f, 0.f, 0.f, 0.f};
                acc = __builtin_amdgcn_mfma_f32_16x16x32_bf16(*(const bf16x8*)&gr[mt][0], wa0, acc, 0, 0, 0);
                acc = __builtin_amdgcn_mfma_f32_16x16x32_bf16(*(const bf16x8*)&gr[mt][1], wa1, acc, 0, 0, 0);
                acc = __builtin_amdgcn_mfma_f32_16x16x32_bf16(*(const bf16x8*)&gc[mt][0], wb0, acc, 0, 0, 0);
                acc = __builtin_amdgcn_mfma_f32_16x16x32_bf16(*(const bf16x8*)&gc[mt][1], wb1, acc, 0, 0, 0);
                // D map (HW-verified): col = lane&15 = hid (nt*16+r),
                //                      row = q*4 + j  = edge (mt*16 + q*4 + j)
#pragma unroll
                for (int j = 0; j < 4; ++j)
                    part[mt][j] = fmaf(fmaxf(acc[j] + bias[nt], 0.f), w2r[nt], part[mt][j]);
            }
        }

        // reduce over the 16 hid-lanes (r) and store 16B per (mt, q-group)
#pragma unroll
        for (int mt = 0; mt < 4; ++mt) {
            float4 o;
            float* po = (float*)&o;
#pragma unroll
            for (int j = 0; j < 4; ++j) {
                float p = part[mt][j];
                p += __shfl_xor(p, 1);
                p += __shfl_xor(p, 2);
                p += __shfl_xor(p, 4);
                p += __shfl_xor(p, 8);
                po[j] = p + b2v;
            }
            if (r == 0)
                *(float4*)(out + ebase + mt * 16 + q * 4) = o;
        }
    }
}

extern "C" void kernel_launch(void* const* d_in, const int* in_sizes, int n_in,
                              void* d_out, int out_size, void* d_ws, size_t ws_size,
                              hipStream_t stream) {
    const float* z  = (const float*)d_in[0];
    const int*   ei = (const int*)d_in[1];
    const float* W1 = (const float*)d_in[2];
    const float* b1 = (const float*)d_in[3];
    const float* W2 = (const float*)d_in[4];
    const float* b2 = (const float*)d_in[5];
    float* out = (float*)d_out;

    const int n_nodes = in_sizes[0] / HID;     // 100000
    const int E       = in_sizes[1] / 2;       // 3200000
    const int* row = ei;
    const int* col = ei + E;

    unsigned short* zb = (unsigned short*)d_ws;   // [n_nodes][64] bf16, 128B rows

    const int n4 = n_nodes * HID / 8;             // 800000 uint4
    zconv_kernel<<<(n4 + 255) / 256, 256, 0, stream>>>(z, (uint4*)zb, n4);

    const int nchunks = E >> 6;                   // 50000
    edge_mfma_kernel<<<2048, 256, 0, stream>>>(row, col, zb, W1, b1, W2, b2,
                                               out, nchunks);
}